// Round 6
// baseline (2501.228 us; speedup 1.0000x reference)
//
#include <hip/hip_runtime.h>
#include <hip/hip_bf16.h>

#define B_  256
#define T_  256
#define F_  64
#define U_  512
#define NG_ 2048   // 4*U
#define BU_ (B_ * U_)

typedef __attribute__((ext_vector_type(8))) short short8;
typedef __attribute__((ext_vector_type(16))) float floatx16;

__device__ __forceinline__ unsigned short f2bf(float f) {
    union { float f; unsigned int u; } v; v.f = f;
    unsigned int u = v.u;
    return (unsigned short)((u + 0x7FFFu + ((u >> 16) & 1u)) >> 16);
}
__device__ __forceinline__ float bf2f(unsigned short s) {
    union { unsigned int u; float f; } v; v.u = ((unsigned int)s) << 16;
    return v.f;
}

__global__ void cast_x_kernel(const float* __restrict__ x,
                              unsigned short* __restrict__ xb, int n) {
    int i = blockIdx.x * blockDim.x + threadIdx.x;
    if (i < n) xb[i] = f2bf(x[i]);
}

// Pack weights into 32x32x16 MFMA B-fragments, per unit-group (16 units -> 64
// block-local gate cols = 2 n32 tiles: [i16|f16] [g16|o16]).
__global__ void pack32_kernel(const float* __restrict__ W, const float* __restrict__ Uw,
                              unsigned short* __restrict__ dst, int KT, int KX) {
    long tid = (long)blockIdx.x * blockDim.x + threadIdx.x;
    long total = 32L * 2 * KT * 512;
    if (tid >= total) return;
    int j    = (int)(tid & 7);
    int lane = (int)((tid >> 3) & 63);
    int p512 = (int)(tid >> 9);
    int kt   = p512 % KT;
    int q    = p512 / KT;
    int nt   = q & 1;
    int ug   = q >> 1;
    int c    = nt * 32 + (lane & 31);
    int srcn = (c >> 4) * U_ + ug * 16 + (c & 15);
    int k    = kt * 16 + (lane >> 5) * 8 + j;
    float v  = (k < KX) ? W[(long)k * NG_ + srcn] : Uw[(long)(k - KX) * NG_ + srcn];
    dst[tid] = f2bf(v);
}

// 16-B h-fragment load as 2x u64 relaxed agent atomics (LLC-coherent, no
// cache-maintenance instructions).
__device__ __forceinline__ short8 ld_frag(const unsigned short* p) {
    union { unsigned long long q[2]; short8 v; } u;
    const unsigned long long* qp = (const unsigned long long*)p;
    u.q[0] = __hip_atomic_load(qp,     __ATOMIC_RELAXED, __HIP_MEMORY_SCOPE_AGENT);
    u.q[1] = __hip_atomic_load(qp + 1, __ATOMIC_RELAXED, __HIP_MEMORY_SCOPE_AGENT);
    return u.v;
}

#define MFMA32(a, b, c) __builtin_amdgcn_mfma_f32_32x32x16_bf16(a, b, c, 0, 0, 0)

// Flags: one 128-B line per (mo,ug) producer: f[(mo*32+ug)*32]. Only wave 3
// polls; lanes 0..31 watch f1 lines, lanes 32..63 watch f2 lines.
__device__ __forceinline__ void wait_top(const int* f1, const int* f2, int k, int lane) {
    const int lug = lane & 31;
    const int* p  = (lane < 32) ? (f1 + lug * 32) : (f2 + lug * 32);
    const int tgt = (lane < 32) ? k : (k - 1);
    int guard = 0;
    for (;;) {
        int v = __hip_atomic_load(p, __ATOMIC_RELAXED, __HIP_MEMORY_SCOPE_AGENT);
        if (__ballot(v >= tgt) == ~0ull) break;
        __builtin_amdgcn_s_sleep(1);
        if (++guard > (1 << 21)) break;   // fail visibly, never hang
    }
}

// Persistent 2-layer LSTM. 256 blocks x 256 thr = 1 block/CU.
// mo = bid % 8 -> communicating blocks share an XCD (perf heuristic only;
// correctness is LLC-level). iter k: phase A = L1 step k, phase B = L2 step
// k-1. Weights in VGPRs. No cache-maintenance ops in the loop; all cross-
// block data/flags via relaxed agent atomics (sc1 -> LLC).
__global__ __launch_bounds__(256, 1) void lstm_persist(
    const unsigned short* __restrict__ xb,
    const unsigned short* __restrict__ P1,
    const unsigned short* __restrict__ P2,
    const float* __restrict__ b1, const float* __restrict__ b2,
    unsigned short* __restrict__ h1r, unsigned short* __restrict__ h2r,
    int* flags1, int* flags2)
{
    const int bid  = blockIdx.x;     // 0..255
    const int mo   = bid & 7;        // m-octile == XCD
    const int ug   = bid >> 3;       // 32 unit-groups of 16 units
    const int tid  = threadIdx.x;
    const int w    = tid >> 6;       // wave 0..3 (k-split)
    const int lane = tid & 63;
    const int arow = lane & 31;
    const int koff = (lane >> 5) * 8;
    const int row  = mo * 32 + arow;

    int* f1 = flags1 + mo * 32 * 32;   // this mo-group's 32 flag lines
    int* f2 = flags2 + mo * 32 * 32;

    __shared__ float red[4][2][32][33];
    __shared__ float cst1[32][16];
    __shared__ float cst2[32][16];
    __shared__ float bias1_s[64], bias2_s[64];

    for (int i = tid; i < 512; i += 256) {
        cst1[i >> 4][i & 15] = 0.f;
        cst2[i >> 4][i & 15] = 0.f;
    }
    if (tid < 64) {
        bias1_s[tid] = b1[(tid >> 4) * U_ + ug * 16 + (tid & 15)];
        bias2_s[tid] = b2[(tid >> 4) * U_ + ug * 16 + (tid & 15)];
    }

    // ---- load BOTH layers' B-fragments into registers (once) ----
    short8 a1f0[9], a1f1[9];     // L1: 36 ktiles of K=16, 9 per wave
    {
        const unsigned short* base = P1 + (size_t)ug * (2 * 36 * 512);
        #pragma unroll
        for (int i = 0; i < 9; ++i) {
            a1f0[i] = *(const short8*)(base + ((size_t)(0 * 36 + w * 9 + i) * 64 + lane) * 8);
            a1f1[i] = *(const short8*)(base + ((size_t)(1 * 36 + w * 9 + i) * 64 + lane) * 8);
        }
    }
    short8 b2f0[16], b2f1[16];   // L2: 64 ktiles; w0,w1 -> U2 half; w2,w3 -> W2 half
    {
        const unsigned short* base = P2 + (size_t)ug * (2 * 64 * 512);
        const int fb = (w < 2) ? (32 + w * 16) : ((w - 2) * 16);
        #pragma unroll
        for (int i = 0; i < 16; ++i) {
            b2f0[i] = *(const short8*)(base + ((size_t)(0 * 64 + fb + i) * 64 + lane) * 8);
            b2f1[i] = *(const short8*)(base + ((size_t)(1 * 64 + fb + i) * 64 + lane) * 8);
        }
    }
    __syncthreads();

    for (int k = 0; k <= T_; ++k) {
        // ---- merged top wait: f1>=k (h1[k-1] for A and B), f2>=k-1 (h2[t2-1])
        floatx16 accA0, accA1;
        #pragma unroll
        for (int i = 0; i < 16; ++i) { accA0[i] = 0.f; accA1[i] = 0.f; }

        if (w == 0) {
            if (k < T_) {   // x-part MFMAs: flag-independent, overlap the poll
                const unsigned short* xbase = xb + ((size_t)row * T_ + k) * F_;
                #pragma unroll
                for (int i = 0; i < 4; ++i) {
                    short8 a = *(const short8*)(xbase + i * 16 + koff);
                    accA0 = MFMA32(a, a1f0[i], accA0);
                    accA1 = MFMA32(a, a1f1[i], accA1);
                }
            }
        } else if (w == 3) {
            wait_top(f1, f2, k, lane);
        }
        __syncthreads();
        __atomic_signal_fence(__ATOMIC_ACQUIRE);

        // ================= phase A : layer-1 step t = k =================
        if (k < T_) {
            if (w == 0) {
                if (k > 0) {
                    const unsigned short* hb = h1r + (size_t)((k - 1) & 3) * BU_
                                               + (size_t)row * U_;
                    #pragma unroll
                    for (int i = 4; i < 9; ++i) {
                        short8 a = ld_frag(hb + (i - 4) * 16 + koff);
                        accA0 = MFMA32(a, a1f0[i], accA0);
                        accA1 = MFMA32(a, a1f1[i], accA1);
                    }
                }
            } else if (k > 0) {
                const unsigned short* hb = h1r + (size_t)((k - 1) & 3) * BU_
                                           + (size_t)row * U_ + (w * 9 - 4) * 16;
                #pragma unroll
                for (int i = 0; i < 9; ++i) {
                    short8 a = ld_frag(hb + i * 16 + koff);
                    accA0 = MFMA32(a, a1f0[i], accA0);
                    accA1 = MFMA32(a, a1f1[i], accA1);
                }
            }

            // D layout: col=lane&31, row=(r&3)+8*(r>>2)+4*(lane>>5)
            #pragma unroll
            for (int r = 0; r < 16; ++r) {
                int rr = (r & 3) + 8 * (r >> 2) + 4 * (lane >> 5);
                red[w][0][rr][arow] = accA0[r];
                red[w][1][rr][arow] = accA1[r];
            }
            __syncthreads();

            {   // epilogue: 256 thr = 32 rows x 8 unit-pairs; one u32 sc1 store
                int u2 = (tid & 7) * 2;
                int r  = tid >> 3;
                unsigned int pk = 0;
                #pragma unroll
                for (int du = 0; du < 2; ++du) {
                    int u = u2 + du;
                    float zi = 0.f, zf = 0.f, zg = 0.f, zo = 0.f;
                    #pragma unroll
                    for (int ww = 0; ww < 4; ++ww) {
                        zi += red[ww][0][r][u];
                        zf += red[ww][0][r][16 + u];
                        zg += red[ww][1][r][u];
                        zo += red[ww][1][r][16 + u];
                    }
                    zi += bias1_s[u];      zf += bias1_s[16 + u];
                    zg += bias1_s[32 + u]; zo += bias1_s[48 + u];
                    float si = 1.f / (1.f + __expf(-zi));
                    float sf = 1.f / (1.f + __expf(-zf));
                    float so = 1.f / (1.f + __expf(-zo));
                    float gg = zg > 0.f ? zg : 0.f;
                    float cn = sf * cst1[r][u] + si * gg;
                    cst1[r][u] = cn;
                    float hn = so * (cn > 0.f ? cn : 0.f);
                    pk |= ((unsigned int)f2bf(hn)) << (16 * du);
                }
                unsigned int* hp = (unsigned int*)(h1r + (size_t)(k & 3) * BU_
                                   + (size_t)(mo * 32 + r) * U_ + ug * 16 + u2);
                __hip_atomic_store(hp, pk, __ATOMIC_RELAXED, __HIP_MEMORY_SCOPE_AGENT);
            }
            __syncthreads();   // every wave's sc1 h-stores drained (vmcnt0)
            __atomic_signal_fence(__ATOMIC_RELEASE);
            if (tid == 0)
                __hip_atomic_store(f1 + ug * 32, k + 1, __ATOMIC_RELAXED,
                                   __HIP_MEMORY_SCOPE_AGENT);
        }

        // ================= phase B : layer-2 step t2 = k-1 =================
        if (k >= 1) {
            const int t2 = k - 1;
            floatx16 acc0, acc1;
            #pragma unroll
            for (int i = 0; i < 16; ++i) { acc0[i] = 0.f; acc1[i] = 0.f; }

            if (w < 2) {
                if (t2 > 0) {               // U2 * h2[t2-1] half
                    const unsigned short* hb = h2r + (size_t)((t2 - 1) & 3) * BU_
                                               + (size_t)row * U_ + (w * 16) * 16;
                    #pragma unroll
                    for (int i = 0; i < 16; ++i) {
                        short8 a = ld_frag(hb + i * 16 + koff);
                        acc0 = MFMA32(a, b2f0[i], acc0);
                        acc1 = MFMA32(a, b2f1[i], acc1);
                    }
                }
            } else {
                // W2 * h1[t2] half — covered by top wait f1 >= k
                const unsigned short* hb = h1r + (size_t)(t2 & 3) * BU_
                                           + (size_t)row * U_ + ((w - 2) * 16) * 16;
                #pragma unroll
                for (int i = 0; i < 16; ++i) {
                    short8 a = ld_frag(hb + i * 16 + koff);
                    acc0 = MFMA32(a, b2f0[i], acc0);
                    acc1 = MFMA32(a, b2f1[i], acc1);
                }
            }

            #pragma unroll
            for (int r = 0; r < 16; ++r) {
                int rr = (r & 3) + 8 * (r >> 2) + 4 * (lane >> 5);
                red[w][0][rr][arow] = acc0[r];
                red[w][1][rr][arow] = acc1[r];
            }
            __syncthreads();

            {
                int u2 = (tid & 7) * 2;
                int r  = tid >> 3;
                unsigned int pk = 0;
                #pragma unroll
                for (int du = 0; du < 2; ++du) {
                    int u = u2 + du;
                    float zi = 0.f, zf = 0.f, zg = 0.f, zo = 0.f;
                    #pragma unroll
                    for (int ww = 0; ww < 4; ++ww) {
                        zi += red[ww][0][r][u];
                        zf += red[ww][0][r][16 + u];
                        zg += red[ww][1][r][u];
                        zo += red[ww][1][r][16 + u];
                    }
                    zi += bias2_s[u];      zf += bias2_s[16 + u];
                    zg += bias2_s[32 + u]; zo += bias2_s[48 + u];
                    float si = 1.f / (1.f + __expf(-zi));
                    float sf = 1.f / (1.f + __expf(-zf));
                    float so = 1.f / (1.f + __expf(-zo));
                    float gg = zg > 0.f ? zg : 0.f;
                    float cn = sf * cst2[r][u] + si * gg;
                    cst2[r][u] = cn;
                    float hn = so * (cn > 0.f ? cn : 0.f);
                    pk |= ((unsigned int)f2bf(hn)) << (16 * du);
                }
                unsigned int* hp = (unsigned int*)(h2r + (size_t)(t2 & 3) * BU_
                                   + (size_t)(mo * 32 + r) * U_ + ug * 16 + u2);
                __hip_atomic_store(hp, pk, __ATOMIC_RELAXED, __HIP_MEMORY_SCOPE_AGENT);
            }
            __syncthreads();
            __atomic_signal_fence(__ATOMIC_RELEASE);
            if (tid == 0)
                __hip_atomic_store(f2 + ug * 32, t2 + 1, __ATOMIC_RELAXED,
                                   __HIP_MEMORY_SCOPE_AGENT);
        }
    }
}

__global__ void dense_kernel(const unsigned short* __restrict__ h2,
                             const float* __restrict__ Wd,
                             const float* __restrict__ bd,
                             float* __restrict__ out) {
    int b = blockIdx.x;
    int lane = threadIdx.x;                  // 64 lanes
    const unsigned short* hp = h2 + (long)b * U_ + lane * 8;
    float sum = 0.f;
    #pragma unroll
    for (int j = 0; j < 8; ++j) sum += bf2f(hp[j]) * Wd[lane * 8 + j];
    #pragma unroll
    for (int off = 32; off; off >>= 1) sum += __shfl_down(sum, off);
    if (lane == 0) out[b] = 1.f / (1.f + __expf(-(sum + bd[0])));
}

extern "C" void kernel_launch(void* const* d_in, const int* in_sizes, int n_in,
                              void* d_out, int out_size, void* d_ws, size_t ws_size,
                              hipStream_t stream) {
    const float* x  = (const float*)d_in[0];
    const float* W1 = (const float*)d_in[1];
    const float* U1 = (const float*)d_in[2];
    const float* b1 = (const float*)d_in[3];
    const float* W2 = (const float*)d_in[4];
    const float* U2 = (const float*)d_in[5];
    const float* b2 = (const float*)d_in[6];
    const float* Wd = (const float*)d_in[7];
    const float* bd = (const float*)d_in[8];
    float* out = (float*)d_out;

    char* ws = (char*)d_ws;
    size_t off = 0;
    unsigned short* xb  = (unsigned short*)(ws + off); off += (size_t)B_ * T_ * F_ * 2;      // 8.39 MB
    unsigned short* P1  = (unsigned short*)(ws + off); off += (size_t)32 * 2 * 36 * 512 * 2; // 2.36 MB
    unsigned short* P2  = (unsigned short*)(ws + off); off += (size_t)32 * 2 * 64 * 512 * 2; // 4.19 MB
    unsigned short* h1r = (unsigned short*)(ws + off); off += (size_t)4 * BU_ * 2;           // 1 MB
    unsigned short* h2r = (unsigned short*)(ws + off); off += (size_t)4 * BU_ * 2;           // 1 MB
    int* flags1 = (int*)(ws + off); off += (size_t)8 * 32 * 32 * 4;   // 32 KB (128B/flag)
    int* flags2 = (int*)(ws + off); off += (size_t)8 * 32 * 32 * 4;   // 32 KB

    hipMemsetAsync(flags1, 0, (size_t)8 * 32 * 32 * 4 * 2, stream);

    int n = B_ * T_ * F_;
    cast_x_kernel<<<(n + 255) / 256, 256, 0, stream>>>(x, xb, n);
    {
        long tot1 = 32L * 2 * 36 * 512;
        pack32_kernel<<<(int)((tot1 + 255) / 256), 256, 0, stream>>>(W1, U1, P1, 36, 64);
        long tot2 = 32L * 2 * 64 * 512;
        pack32_kernel<<<(int)((tot2 + 255) / 256), 256, 0, stream>>>(W2, U2, P2, 64, 512);
    }

    // 256 blocks = 1 block/CU: co-residency guaranteed, plain launch.
    lstm_persist<<<256, 256, 0, stream>>>(xb, P1, P2, b1, b2, h1r, h2r, flags1, flags2);

    dense_kernel<<<B_, 64, 0, stream>>>(h2r + (size_t)((T_ - 1) & 3) * BU_,
                                        Wd, bd, out);
}

// Round 7
// 1850.684 us; speedup vs baseline: 1.3515x; 1.3515x over previous
//
#include <hip/hip_runtime.h>
#include <hip/hip_bf16.h>

#define B_  256
#define T_  256
#define F_  64
#define U_  512
#define NG_ 2048   // 4*U
#define BU_ (B_ * U_)

typedef __attribute__((ext_vector_type(8))) short short8;
typedef __attribute__((ext_vector_type(16))) float floatx16;

__device__ __forceinline__ unsigned short f2bf(float f) {
    union { float f; unsigned int u; } v; v.f = f;
    unsigned int u = v.u;
    return (unsigned short)((u + 0x7FFFu + ((u >> 16) & 1u)) >> 16);
}
__device__ __forceinline__ float bf2f(unsigned short s) {
    union { unsigned int u; float f; } v; v.u = ((unsigned int)s) << 16;
    return v.f;
}

__global__ void cast_x_kernel(const float* __restrict__ x,
                              unsigned short* __restrict__ xb, int n) {
    int i = blockIdx.x * blockDim.x + threadIdx.x;
    if (i < n) xb[i] = f2bf(x[i]);
}

// Pack weights into 32x32x16 MFMA B-fragments, per unit-group (16 units -> 64
// block-local gate cols = 2 n32 tiles: [i16|f16] [g16|o16]).
__global__ void pack32_kernel(const float* __restrict__ W, const float* __restrict__ Uw,
                              unsigned short* __restrict__ dst, int KT, int KX) {
    long tid = (long)blockIdx.x * blockDim.x + threadIdx.x;
    long total = 32L * 2 * KT * 512;
    if (tid >= total) return;
    int j    = (int)(tid & 7);
    int lane = (int)((tid >> 3) & 63);
    int p512 = (int)(tid >> 9);
    int kt   = p512 % KT;
    int q    = p512 / KT;
    int nt   = q & 1;
    int ug   = q >> 1;
    int c    = nt * 32 + (lane & 31);
    int srcn = (c >> 4) * U_ + ug * 16 + (c & 15);
    int k    = kt * 16 + (lane >> 5) * 8 + j;
    float v  = (k < KX) ? W[(long)k * NG_ + srcn] : Uw[(long)(k - KX) * NG_ + srcn];
    dst[tid] = f2bf(v);
}

// LLC-coherent 16-B load, NON-atomic: batched issue, latency overlaps.
__device__ __forceinline__ short8 llc_load(const unsigned short* p) {
    short8 r;
    asm volatile("global_load_dwordx4 %0, %1, off sc0 sc1" : "=v"(r) : "v"(p));
    return r;
}
#define VMWAIT(N) asm volatile("s_waitcnt vmcnt(" #N ")" ::: "memory")
// Pin a frag register: volatile asm keeps order vs VMWAIT, and the MFMA's
// operand is defined here -> MFMA cannot be scheduled above the wait.
__device__ __forceinline__ void dep8(short8& x) { asm volatile("" : "+v"(x)); }

#define MFMA32(a, b, c) __builtin_amdgcn_mfma_f32_32x32x16_bf16(a, b, c, 0, 0, 0)

// Flags: one 128-B line per (mo,ug) producer. Only wave 3 polls; lanes 0..31
// watch f1 lines, lanes 32..63 watch f2 lines.
__device__ __forceinline__ void wait_top(const int* f1, const int* f2, int k, int lane) {
    const int lug = lane & 31;
    const int* p  = (lane < 32) ? (f1 + lug * 32) : (f2 + lug * 32);
    const int tgt = (lane < 32) ? k : (k - 1);
    int guard = 0;
    for (;;) {
        int v = __hip_atomic_load(p, __ATOMIC_RELAXED, __HIP_MEMORY_SCOPE_AGENT);
        if (__ballot(v >= tgt) == ~0ull) break;
        __builtin_amdgcn_s_sleep(1);
        if (++guard > (1 << 21)) break;   // fail visibly, never hang
    }
}

// Persistent 2-layer LSTM. 256 blocks x 256 thr = 1 block/CU.
// iter k: phase A = L1 step k, phase B = L2 step k-1. Weights in VGPRs.
// All cross-block data via sc0+sc1 loads / sc1 stores (LLC coherence point);
// no cache-maintenance instructions anywhere in the loop.
__global__ __launch_bounds__(256, 1) void lstm_persist(
    const unsigned short* __restrict__ xb,
    const unsigned short* __restrict__ P1,
    const unsigned short* __restrict__ P2,
    const float* __restrict__ b1, const float* __restrict__ b2,
    unsigned short* __restrict__ h1r, unsigned short* __restrict__ h2r,
    int* flags1, int* flags2)
{
    const int bid  = blockIdx.x;     // 0..255
    const int mo   = bid & 7;        // m-octile == XCD (locality heuristic)
    const int ug   = bid >> 3;       // 32 unit-groups of 16 units
    const int tid  = threadIdx.x;
    const int w    = tid >> 6;       // wave 0..3 (k-split)
    const int lane = tid & 63;
    const int arow = lane & 31;
    const int koff = (lane >> 5) * 8;
    const int row  = mo * 32 + arow;

    int* f1 = flags1 + mo * 32 * 32;
    int* f2 = flags2 + mo * 32 * 32;

    __shared__ float red[4][2][32][33];
    __shared__ float cst1[32][16];
    __shared__ float cst2[32][16];
    __shared__ float bias1_s[64], bias2_s[64];

    for (int i = tid; i < 512; i += 256) {
        cst1[i >> 4][i & 15] = 0.f;
        cst2[i >> 4][i & 15] = 0.f;
    }
    if (tid < 64) {
        bias1_s[tid] = b1[(tid >> 4) * U_ + ug * 16 + (tid & 15)];
        bias2_s[tid] = b2[(tid >> 4) * U_ + ug * 16 + (tid & 15)];
    }

    // ---- load BOTH layers' B-fragments into registers (once) ----
    short8 a1f0[9], a1f1[9];     // L1: 36 ktiles of K=16, 9 per wave
    {
        const unsigned short* base = P1 + (size_t)ug * (2 * 36 * 512);
        #pragma unroll
        for (int i = 0; i < 9; ++i) {
            a1f0[i] = *(const short8*)(base + ((size_t)(0 * 36 + w * 9 + i) * 64 + lane) * 8);
            a1f1[i] = *(const short8*)(base + ((size_t)(1 * 36 + w * 9 + i) * 64 + lane) * 8);
        }
    }
    short8 b2f0[16], b2f1[16];   // L2: 64 ktiles; w0,w1 -> U2 half; w2,w3 -> W2 half
    {
        const unsigned short* base = P2 + (size_t)ug * (2 * 64 * 512);
        const int fb = (w < 2) ? (32 + w * 16) : ((w - 2) * 16);
        #pragma unroll
        for (int i = 0; i < 16; ++i) {
            b2f0[i] = *(const short8*)(base + ((size_t)(0 * 64 + fb + i) * 64 + lane) * 8);
            b2f1[i] = *(const short8*)(base + ((size_t)(1 * 64 + fb + i) * 64 + lane) * 8);
        }
    }
    __syncthreads();

    for (int k = 0; k <= T_; ++k) {
        const int t2 = k - 1;
        floatx16 accA0, accA1;
        #pragma unroll
        for (int i = 0; i < 16; ++i) { accA0[i] = 0.f; accA1[i] = 0.f; }

        // ---- pre-barrier: w0 computes x-part (flag-free), w3 polls flags
        if (w == 0) {
            if (k < T_) {
                const unsigned short* xbase = xb + ((size_t)row * T_ + k) * F_;
                #pragma unroll
                for (int i = 0; i < 4; ++i) {
                    short8 a = *(const short8*)(xbase + i * 16 + koff);
                    accA0 = MFMA32(a, a1f0[i], accA0);
                    accA1 = MFMA32(a, a1f1[i], accA1);
                }
            }
        } else if (w == 3) {
            wait_top(f1, f2, k, lane);
        }
        __syncthreads();
        __atomic_signal_fence(__ATOMIC_ACQUIRE);

        // ---- issue ALL of this iteration's h loads, batched ----
        short8 fA[9];
        const int nA = (k > 0 && k < T_) ? ((w == 0) ? 5 : 9) : 0;
        if (k > 0 && k < T_) {
            if (w == 0) {
                const unsigned short* hb = h1r + (size_t)((k - 1) & 3) * BU_
                                           + (size_t)row * U_;
                #pragma unroll
                for (int i = 0; i < 5; ++i) fA[i] = llc_load(hb + i * 16 + koff);
            } else {
                const unsigned short* hb = h1r + (size_t)((k - 1) & 3) * BU_
                                           + (size_t)row * U_ + (w * 9 - 4) * 16;
                #pragma unroll
                for (int i = 0; i < 9; ++i) fA[i] = llc_load(hb + i * 16 + koff);
            }
        }
        short8 fB[16];
        bool haveB = false;
        if (k >= 1) {
            if (w < 2) {
                if (t2 > 0) {
                    const unsigned short* hb = h2r + (size_t)((t2 - 1) & 3) * BU_
                                               + (size_t)row * U_ + (w * 16) * 16;
                    #pragma unroll
                    for (int i = 0; i < 16; ++i) fB[i] = llc_load(hb + i * 16 + koff);
                    haveB = true;
                }
            } else {
                const unsigned short* hb = h1r + (size_t)(t2 & 3) * BU_
                                           + (size_t)row * U_ + ((w - 2) * 16) * 16;
                #pragma unroll
                for (int i = 0; i < 16; ++i) fB[i] = llc_load(hb + i * 16 + koff);
                haveB = true;
            }
        }

        // ================= phase A : layer-1 step t = k =================
        if (k < T_) {
            if (nA > 0) {
                if (haveB) { VMWAIT(16); } else { VMWAIT(0); }
                if (w == 0) {
                    #pragma unroll
                    for (int i = 0; i < 5; ++i) {
                        dep8(fA[i]);
                        accA0 = MFMA32(fA[i], a1f0[4 + i], accA0);
                        accA1 = MFMA32(fA[i], a1f1[4 + i], accA1);
                    }
                } else {
                    #pragma unroll
                    for (int i = 0; i < 9; ++i) {
                        dep8(fA[i]);
                        accA0 = MFMA32(fA[i], a1f0[i], accA0);
                        accA1 = MFMA32(fA[i], a1f1[i], accA1);
                    }
                }
            }

            // D layout: col=lane&31, row=(r&3)+8*(r>>2)+4*(lane>>5)
            #pragma unroll
            for (int r = 0; r < 16; ++r) {
                int rr = (r & 3) + 8 * (r >> 2) + 4 * (lane >> 5);
                red[w][0][rr][arow] = accA0[r];
                red[w][1][rr][arow] = accA1[r];
            }
            __syncthreads();

            {   // epilogue: 256 thr = 32 rows x 8 unit-pairs; one u32 sc1 store
                int u2 = (tid & 7) * 2;
                int r  = tid >> 3;
                unsigned int pk = 0;
                #pragma unroll
                for (int du = 0; du < 2; ++du) {
                    int u = u2 + du;
                    float zi = 0.f, zf = 0.f, zg = 0.f, zo = 0.f;
                    #pragma unroll
                    for (int ww = 0; ww < 4; ++ww) {
                        zi += red[ww][0][r][u];
                        zf += red[ww][0][r][16 + u];
                        zg += red[ww][1][r][u];
                        zo += red[ww][1][r][16 + u];
                    }
                    zi += bias1_s[u];      zf += bias1_s[16 + u];
                    zg += bias1_s[32 + u]; zo += bias1_s[48 + u];
                    float si = 1.f / (1.f + __expf(-zi));
                    float sf = 1.f / (1.f + __expf(-zf));
                    float so = 1.f / (1.f + __expf(-zo));
                    float gg = zg > 0.f ? zg : 0.f;
                    float cn = sf * cst1[r][u] + si * gg;
                    cst1[r][u] = cn;
                    float hn = so * (cn > 0.f ? cn : 0.f);
                    pk |= ((unsigned int)f2bf(hn)) << (16 * du);
                }
                unsigned int* hp = (unsigned int*)(h1r + (size_t)(k & 3) * BU_
                                   + (size_t)(mo * 32 + r) * U_ + ug * 16 + u2);
                __hip_atomic_store(hp, pk, __ATOMIC_RELAXED, __HIP_MEMORY_SCOPE_AGENT);
            }
            __syncthreads();   // h1 sc1 stores drained (vmcnt0) for all waves
            __atomic_signal_fence(__ATOMIC_RELEASE);
            if (tid == 0)
                __hip_atomic_store(f1 + ug * 32, k + 1, __ATOMIC_RELAXED,
                                   __HIP_MEMORY_SCOPE_AGENT);
        }

        // ================= phase B : layer-2 step t2 = k-1 =================
        if (k >= 1) {
            floatx16 acc0, acc1;
            #pragma unroll
            for (int i = 0; i < 16; ++i) { acc0[i] = 0.f; acc1[i] = 0.f; }

            if (haveB) {
                VMWAIT(0);
                const short8* bw0 = (w < 2) ? b2f0 : b2f0;  // same arrays; role set at init
                #pragma unroll
                for (int i = 0; i < 16; ++i) {
                    dep8(fB[i]);
                    acc0 = MFMA32(fB[i], b2f0[i], acc0);
                    acc1 = MFMA32(fB[i], b2f1[i], acc1);
                }
                (void)bw0;
            }

            #pragma unroll
            for (int r = 0; r < 16; ++r) {
                int rr = (r & 3) + 8 * (r >> 2) + 4 * (lane >> 5);
                red[w][0][rr][arow] = acc0[r];
                red[w][1][rr][arow] = acc1[r];
            }
            __syncthreads();

            {
                int u2 = (tid & 7) * 2;
                int r  = tid >> 3;
                unsigned int pk = 0;
                #pragma unroll
                for (int du = 0; du < 2; ++du) {
                    int u = u2 + du;
                    float zi = 0.f, zf = 0.f, zg = 0.f, zo = 0.f;
                    #pragma unroll
                    for (int ww = 0; ww < 4; ++ww) {
                        zi += red[ww][0][r][u];
                        zf += red[ww][0][r][16 + u];
                        zg += red[ww][1][r][u];
                        zo += red[ww][1][r][16 + u];
                    }
                    zi += bias2_s[u];      zf += bias2_s[16 + u];
                    zg += bias2_s[32 + u]; zo += bias2_s[48 + u];
                    float si = 1.f / (1.f + __expf(-zi));
                    float sf = 1.f / (1.f + __expf(-zf));
                    float so = 1.f / (1.f + __expf(-zo));
                    float gg = zg > 0.f ? zg : 0.f;
                    float cn = sf * cst2[r][u] + si * gg;
                    cst2[r][u] = cn;
                    float hn = so * (cn > 0.f ? cn : 0.f);
                    pk |= ((unsigned int)f2bf(hn)) << (16 * du);
                }
                unsigned int* hp = (unsigned int*)(h2r + (size_t)(t2 & 3) * BU_
                                   + (size_t)(mo * 32 + r) * U_ + ug * 16 + u2);
                __hip_atomic_store(hp, pk, __ATOMIC_RELAXED, __HIP_MEMORY_SCOPE_AGENT);
            }
            __syncthreads();
            __atomic_signal_fence(__ATOMIC_RELEASE);
            if (tid == 0)
                __hip_atomic_store(f2 + ug * 32, t2 + 1, __ATOMIC_RELAXED,
                                   __HIP_MEMORY_SCOPE_AGENT);
        }
    }
}

__global__ void dense_kernel(const unsigned short* __restrict__ h2,
                             const float* __restrict__ Wd,
                             const float* __restrict__ bd,
                             float* __restrict__ out) {
    int b = blockIdx.x;
    int lane = threadIdx.x;                  // 64 lanes
    const unsigned short* hp = h2 + (long)b * U_ + lane * 8;
    float sum = 0.f;
    #pragma unroll
    for (int j = 0; j < 8; ++j) sum += bf2f(hp[j]) * Wd[lane * 8 + j];
    #pragma unroll
    for (int off = 32; off; off >>= 1) sum += __shfl_down(sum, off);
    if (lane == 0) out[b] = 1.f / (1.f + __expf(-(sum + bd[0])));
}

extern "C" void kernel_launch(void* const* d_in, const int* in_sizes, int n_in,
                              void* d_out, int out_size, void* d_ws, size_t ws_size,
                              hipStream_t stream) {
    const float* x  = (const float*)d_in[0];
    const float* W1 = (const float*)d_in[1];
    const float* U1 = (const float*)d_in[2];
    const float* b1 = (const float*)d_in[3];
    const float* W2 = (const float*)d_in[4];
    const float* U2 = (const float*)d_in[5];
    const float* b2 = (const float*)d_in[6];
    const float* Wd = (const float*)d_in[7];
    const float* bd = (const float*)d_in[8];
    float* out = (float*)d_out;

    char* ws = (char*)d_ws;
    size_t off = 0;
    unsigned short* xb  = (unsigned short*)(ws + off); off += (size_t)B_ * T_ * F_ * 2;      // 8.39 MB
    unsigned short* P1  = (unsigned short*)(ws + off); off += (size_t)32 * 2 * 36 * 512 * 2; // 2.36 MB
    unsigned short* P2  = (unsigned short*)(ws + off); off += (size_t)32 * 2 * 64 * 512 * 2; // 4.19 MB
    unsigned short* h1r = (unsigned short*)(ws + off); off += (size_t)4 * BU_ * 2;           // 1 MB
    unsigned short* h2r = (unsigned short*)(ws + off); off += (size_t)4 * BU_ * 2;           // 1 MB
    int* flags1 = (int*)(ws + off); off += (size_t)8 * 32 * 32 * 4;   // 32 KB (128B/flag)
    int* flags2 = (int*)(ws + off); off += (size_t)8 * 32 * 32 * 4;   // 32 KB

    hipMemsetAsync(flags1, 0, (size_t)8 * 32 * 32 * 4 * 2, stream);

    int n = B_ * T_ * F_;
    cast_x_kernel<<<(n + 255) / 256, 256, 0, stream>>>(x, xb, n);
    {
        long tot1 = 32L * 2 * 36 * 512;
        pack32_kernel<<<(int)((tot1 + 255) / 256), 256, 0, stream>>>(W1, U1, P1, 36, 64);
        long tot2 = 32L * 2 * 64 * 512;
        pack32_kernel<<<(int)((tot2 + 255) / 256), 256, 0, stream>>>(W2, U2, P2, 64, 512);
    }

    // 256 blocks = 1 block/CU: co-residency guaranteed, plain launch.
    lstm_persist<<<256, 256, 0, stream>>>(xb, P1, P2, b1, b2, h1r, h2r, flags1, flags2);

    dense_kernel<<<B_, 64, 0, stream>>>(h2r + (size_t)((T_ - 1) & 3) * BU_,
                                        Wd, bd, out);
}